// Round 7
// baseline (279.120 us; speedup 1.0000x reference)
//
#include <hip/hip_runtime.h>
#include <hip/hip_bf16.h>
#include <math.h>

#define BATCH 512
#define EMBED 512
#define NCLS  100000

typedef __attribute__((ext_vector_type(4)))  float f32x4;
typedef __attribute__((ext_vector_type(16))) float f32x16;
typedef __attribute__((ext_vector_type(2)))  long  i64x2;

constexpr float kCOS_M = 0.8775825618903728f;   // cos(0.5)
constexpr float kSIN_M = 0.4794255386042030f;   // sin(0.5)
constexpr float kTHR   = -0.8775825618903728f;  // cos(pi-0.5)
constexpr float kMM    = 0.2397127693021015f;   // sin(pi-0.5)*0.5

__device__ __forceinline__ unsigned cvt4(float a, float b, float c, float d) {
  int v = __builtin_amdgcn_cvt_pk_fp8_f32(a, b, 0, false);
  v = __builtin_amdgcn_cvt_pk_fp8_f32(c, d, v, true);
  return (unsigned)v;
}

// ---------------- K1: normalize embeddings -> fp8 x16, hi-split + XOR-swizzled ----
// Element k of row r lands at byte  slotL*16 + half*8 + k[2:0]  with
// slotL = k[3]<<4 | k[8:5], half = k[4]; physical slot = slotL ^ (r&31).
__global__ void knorm_e(const float* __restrict__ E, unsigned char* __restrict__ En8) {
  int r = blockIdx.x;
  int l = threadIdx.x;                       // 64 lanes; lane owns elems 8l..8l+7
  const f32x4* src = (const f32x4*)(E + r * EMBED);
  f32x4 a = src[2 * l], b = src[2 * l + 1];
  float ss = a.x*a.x + a.y*a.y + a.z*a.z + a.w*a.w
           + b.x*b.x + b.y*b.y + b.z*b.z + b.w*b.w;
#pragma unroll
  for (int d = 1; d < 64; d <<= 1) ss += __shfl_xor(ss, d);
  float s = 16.0f / fmaxf(sqrtf(ss), 1e-12f);
  uint2 pk;
  pk.x = cvt4(a.x * s, a.y * s, a.z * s, a.w * s);
  pk.y = cvt4(b.x * s, b.y * s, b.z * s, b.w * s);
  int slotL = (l & 1) * 16 + (l >> 2);
  int half  = (l >> 1) & 1;
  *(uint2*)(En8 + r * 512 + (((slotL ^ (r & 31)) << 4) | (half << 3))) = pk;
}

// ---------------- K2: label-column cosine + margin in f32 ----------------
__global__ void klabel(const float* __restrict__ E, const float* __restrict__ W,
                       const int* __restrict__ labels,
                       float* __restrict__ lcos, float* __restrict__ lphi)
{
  int r = blockIdx.x * 8 + (threadIdx.x >> 6);
  int l = threadIdx.x & 63;
  int lbl = labels[r];
  const float* ep = E + (size_t)r * EMBED + l * 8;
  const float* wp = W + (size_t)lbl * EMBED + l * 8;
  f32x4 e0 = *(const f32x4*)ep, e1 = *(const f32x4*)(ep + 4);
  f32x4 w0 = *(const f32x4*)wp, w1 = *(const f32x4*)(wp + 4);
  float dot = e0.x*w0.x + e0.y*w0.y + e0.z*w0.z + e0.w*w0.w
            + e1.x*w1.x + e1.y*w1.y + e1.z*w1.z + e1.w*w1.w;
  float se = e0.x*e0.x + e0.y*e0.y + e0.z*e0.z + e0.w*e0.w
           + e1.x*e1.x + e1.y*e1.y + e1.z*e1.z + e1.w*e1.w;
  float sw = w0.x*w0.x + w0.y*w0.y + w0.z*w0.z + w0.w*w0.w
           + w1.x*w1.x + w1.y*w1.y + w1.z*w1.z + w1.w*w1.w;
#pragma unroll
  for (int d = 1; d < 64; d <<= 1) {
    dot += __shfl_xor(dot, d); se += __shfl_xor(se, d); sw += __shfl_xor(sw, d);
  }
  float cosv = dot / (fmaxf(sqrtf(se), 1e-12f) * fmaxf(sqrtf(sw), 1e-12f));
  float cc = fminf(fmaxf(cosv, -1.f), 1.f);
  float sine = sqrtf(fmaxf(1.f - cc * cc, 0.f));
  float phi = (cosv > kTHR) ? (cosv * kCOS_M - sine * kSIN_M) : (cosv - kMM);
  if (l == 0) { lcos[r] = 64.f * cosv; lphi[r] = 64.f * phi; }
}

// ---------------- K3: barrier-free fused fp8 GEMM + fixed-max expsum ----------
// 256 blocks (1/CU) = 8 xcd x 4 panel x 8 slot. A panel LDS-resident (64KB).
// Waves free-run over 32-class strips (strip = xcd + 8*sloc): B fragments are
// built IN REGISTERS (lane = class cl, k-octet hi) from 4-deep double-buffered
// global loads. No barriers, no B LDS, no vmcnt(0) in the main loop.
__global__ __launch_bounds__(512, 1) void kmain(
    const unsigned char* __restrict__ En8, const float* __restrict__ W,
    float* __restrict__ psum)
{
  __shared__ unsigned char Asm[128 * 512];   // 64 KB
  __shared__ float smemS[8][128];

  int bid = blockIdx.x;
  int xcd  = bid & 7;
  int panel = (bid >> 3) & 3;
  int slot = bid >> 5;                       // 0..7

  int tid = threadIdx.x;
  int w = tid >> 6, l = tid & 63;
  int cl = l & 31, hi = l >> 5;

  // ---- stage A panel once: pure linear glds (source pre-swizzled) ----
#pragma unroll
  for (int i = 0; i < 8; ++i) {
    int base = i * 8192 + w * 1024;
    __builtin_amdgcn_global_load_lds(
        (const __attribute__((address_space(1))) void*)(En8 + panel * 65536 + base + l * 16),
        (__attribute__((address_space(3))) void*)(&Asm[base]), 16, 0, 0);
  }

  const unsigned char* Ap0 = (const unsigned char*)Asm + (size_t)cl * 512;
  const unsigned char* Ap1 = Ap0 + 32 * 512;
  const unsigned char* Ap2 = Ap0 + 64 * 512;
  const unsigned char* Ap3 = Ap0 + 96 * 512;

  // job schedule: sloc = slot*8 + w + 64*j  (strip = xcd + 8*sloc < 3125)
  int cnt = ((3124 - xcd) >> 3) + 1;         // 391 (xcd<5) or 390
  int sloc0 = slot * 8 + w;
  int njobs = (cnt - sloc0 + 63) >> 6;       // 6 or 7
  int strip0 = xcd + 8 * sloc0;
  const size_t JSTR = (size_t)512 * 32 * EMBED;   // +512 strips per job
  const float* wjob = W + (size_t)(strip0 * 32 + cl) * EMBED + hi * 8;

  f32x4 Ra0, Ra1, Ra2, Ra3, Rb0, Rb1, Rb2, Rb3;
  f32x4 Rc0, Rc1, Rc2, Rc3, Rd0, Rd1, Rd2, Rd3;
  f32x16 acc0, acc1, acc2, acc3, S0, S1, S2, S3;
#pragma unroll
  for (int e = 0; e < 16; ++e) {
    acc0[e] = 0.f; acc1[e] = 0.f; acc2[e] = 0.f; acc3[e] = 0.f;
    S0[e] = 0.f; S1[e] = 0.f; S2[e] = 0.f; S3[e] = 0.f;
  }
  float ssq = 0.f;

#define LOADP(R0, R1, R2, R3, base, p)                    \
  R0 = *(const f32x4*)((base) + (p) * 32);                \
  R1 = *(const f32x4*)((base) + (p) * 32 + 4);            \
  R2 = *(const f32x4*)((base) + (p) * 32 + 16);           \
  R3 = *(const f32x4*)((base) + (p) * 32 + 20);

#define COMPUTEP(R0, R1, R2, R3, p) {                                          \
    ssq += R0.x*R0.x + R0.y*R0.y + R0.z*R0.z + R0.w*R0.w                       \
         + R1.x*R1.x + R1.y*R1.y + R1.z*R1.z + R1.w*R1.w                       \
         + R2.x*R2.x + R2.y*R2.y + R2.z*R2.z + R2.w*R2.w                       \
         + R3.x*R3.x + R3.y*R3.y + R3.z*R3.z + R3.w*R3.w;                      \
    uint2 bu0, bu1;                                                            \
    bu0.x = cvt4(R0.x*128.f, R0.y*128.f, R0.z*128.f, R0.w*128.f);              \
    bu0.y = cvt4(R1.x*128.f, R1.y*128.f, R1.z*128.f, R1.w*128.f);              \
    bu1.x = cvt4(R2.x*128.f, R2.y*128.f, R2.z*128.f, R2.w*128.f);              \
    bu1.y = cvt4(R3.x*128.f, R3.y*128.f, R3.z*128.f, R3.w*128.f);              \
    long bop0 = __builtin_bit_cast(long, bu0);                                 \
    long bop1 = __builtin_bit_cast(long, bu1);                                 \
    const int so = ((((hi) << 4) | (p)) ^ cl) << 4;                            \
    i64x2 a0 = *(const i64x2*)(Ap0 + so);                                      \
    i64x2 a1 = *(const i64x2*)(Ap1 + so);                                      \
    i64x2 a2 = *(const i64x2*)(Ap2 + so);                                      \
    i64x2 a3 = *(const i64x2*)(Ap3 + so);                                      \
    acc0 = __builtin_amdgcn_mfma_f32_32x32x16_fp8_fp8(a0[0], bop0, acc0,0,0,0);\
    acc0 = __builtin_amdgcn_mfma_f32_32x32x16_fp8_fp8(a0[1], bop1, acc0,0,0,0);\
    acc1 = __builtin_amdgcn_mfma_f32_32x32x16_fp8_fp8(a1[0], bop0, acc1,0,0,0);\
    acc1 = __builtin_amdgcn_mfma_f32_32x32x16_fp8_fp8(a1[1], bop1, acc1,0,0,0);\
    acc2 = __builtin_amdgcn_mfma_f32_32x32x16_fp8_fp8(a2[0], bop0, acc2,0,0,0);\
    acc2 = __builtin_amdgcn_mfma_f32_32x32x16_fp8_fp8(a2[1], bop1, acc2,0,0,0);\
    acc3 = __builtin_amdgcn_mfma_f32_32x32x16_fp8_fp8(a3[0], bop0, acc3,0,0,0);\
    acc3 = __builtin_amdgcn_mfma_f32_32x32x16_fp8_fp8(a3[1], bop1, acc3,0,0,0);\
  }

  // preload pairs 0..3 of job 0, then wait A + sync once
  LOADP(Ra0, Ra1, Ra2, Ra3, wjob, 0)
  LOADP(Rb0, Rb1, Rb2, Rb3, wjob, 1)
  LOADP(Rc0, Rc1, Rc2, Rc3, wjob, 2)
  LOADP(Rd0, Rd1, Rd2, Rd3, wjob, 3)
  __syncthreads();

  for (int j = 0; j < njobs; ++j) {
    const float* wnx = (j + 1 < njobs) ? (wjob + JSTR) : W;
    COMPUTEP(Ra0, Ra1, Ra2, Ra3, 0)  LOADP(Ra0, Ra1, Ra2, Ra3, wjob, 4)
    COMPUTEP(Rb0, Rb1, Rb2, Rb3, 1)  LOADP(Rb0, Rb1, Rb2, Rb3, wjob, 5)
    COMPUTEP(Rc0, Rc1, Rc2, Rc3, 2)  LOADP(Rc0, Rc1, Rc2, Rc3, wjob, 6)
    COMPUTEP(Rd0, Rd1, Rd2, Rd3, 3)  LOADP(Rd0, Rd1, Rd2, Rd3, wjob, 7)
    COMPUTEP(Ra0, Ra1, Ra2, Ra3, 4)  LOADP(Ra0, Ra1, Ra2, Ra3, wjob, 8)
    COMPUTEP(Rb0, Rb1, Rb2, Rb3, 5)  LOADP(Rb0, Rb1, Rb2, Rb3, wjob, 9)
    COMPUTEP(Rc0, Rc1, Rc2, Rc3, 6)  LOADP(Rc0, Rc1, Rc2, Rc3, wjob, 10)
    COMPUTEP(Rd0, Rd1, Rd2, Rd3, 7)  LOADP(Rd0, Rd1, Rd2, Rd3, wjob, 11)
    COMPUTEP(Ra0, Ra1, Ra2, Ra3, 8)  LOADP(Ra0, Ra1, Ra2, Ra3, wjob, 12)
    COMPUTEP(Rb0, Rb1, Rb2, Rb3, 9)  LOADP(Rb0, Rb1, Rb2, Rb3, wjob, 13)
    COMPUTEP(Rc0, Rc1, Rc2, Rc3, 10) LOADP(Rc0, Rc1, Rc2, Rc3, wjob, 14)
    COMPUTEP(Rd0, Rd1, Rd2, Rd3, 11) LOADP(Rd0, Rd1, Rd2, Rd3, wjob, 15)
    COMPUTEP(Ra0, Ra1, Ra2, Ra3, 12) LOADP(Ra0, Ra1, Ra2, Ra3, wnx, 0)
    COMPUTEP(Rb0, Rb1, Rb2, Rb3, 13) LOADP(Rb0, Rb1, Rb2, Rb3, wnx, 1)
    COMPUTEP(Rc0, Rc1, Rc2, Rc3, 14) LOADP(Rc0, Rc1, Rc2, Rc3, wnx, 2)
    COMPUTEP(Rd0, Rd1, Rd2, Rd3, 15) LOADP(Rd0, Rd1, Rd2, Rd3, wnx, 3)
    // ---- job epilogue: per-class rnorm + exp accumulate ----
    float rs = ssq + __shfl_xor(ssq, 32);
    float rn = 0.03125f * rsqrtf(fmaxf(rs, 1e-30f));
#pragma unroll
    for (int e = 0; e < 16; ++e) {
      S0[e] += __expf(fmaf(acc0[e], rn, -64.f)); acc0[e] = 0.f;
      S1[e] += __expf(fmaf(acc1[e], rn, -64.f)); acc1[e] = 0.f;
      S2[e] += __expf(fmaf(acc2[e], rn, -64.f)); acc2[e] = 0.f;
      S3[e] += __expf(fmaf(acc3[e], rn, -64.f)); acc3[e] = 0.f;
    }
    ssq = 0.f;
    wjob = wnx;
  }
#undef LOADP
#undef COMPUTEP

  // ---- fold S across the 32 class-lanes; block-reduce across waves ----
#pragma unroll
  for (int e = 0; e < 16; ++e) {
    float v0 = S0[e], v1 = S1[e], v2 = S2[e], v3 = S3[e];
#pragma unroll
    for (int d = 1; d < 32; d <<= 1) {
      v0 += __shfl_xor(v0, d); v1 += __shfl_xor(v1, d);
      v2 += __shfl_xor(v2, d); v3 += __shfl_xor(v3, d);
    }
    S0[e] = v0; S1[e] = v1; S2[e] = v2; S3[e] = v3;
  }
  if (cl == 0) {
#pragma unroll
    for (int e = 0; e < 16; ++e) {
      int rmap = (e & 3) + 8 * (e >> 2) + 4 * hi;
      smemS[w][rmap]      = S0[e];
      smemS[w][32 + rmap] = S1[e];
      smemS[w][64 + rmap] = S2[e];
      smemS[w][96 + rmap] = S3[e];
    }
  }
  __syncthreads();
  if (tid < 128) {
    float t = 0.f;
#pragma unroll
    for (int q = 0; q < 8; ++q) t += smemS[q][tid];
    psum[bid * 128 + tid] = t;
  }
}

// ---------------- K4: reduce over the 8 slots of each (panel,xcd) ----------
__global__ void kred1(const float* __restrict__ psum, float* __restrict__ pp2) {
  int g = blockIdx.x;            // 0..31: panel = g>>3, xcd = g&7
  int r = threadIdx.x;           // 128
  int panel = g >> 3, xcd = g & 7;
  float s = 0.f;
#pragma unroll
  for (int slot = 0; slot < 8; ++slot)
    s += psum[(xcd + 8 * panel + 32 * slot) * 128 + r];
  pp2[g * 128 + r] = s;
}

// ---------------- K5: final combine + label adjust + NLL mean --------------
__global__ void kfinal(const float* __restrict__ pp2, const float* __restrict__ lcos,
                       const float* __restrict__ lphi, float* __restrict__ out)
{
  int tid = threadIdx.x;         // 512 = one thread per batch row
  int panel = tid >> 7, rl = tid & 127;
  float S = 0.f;
#pragma unroll
  for (int x = 0; x < 8; ++x)
    S += pp2[(panel * 8 + x) * 128 + rl];
  float lc = lcos[tid], lp = lphi[tid];
  S = S - __expf(lc - 64.f) + __expf(lp - 64.f);
  float nll = 64.f + __logf(S) - lp;
#pragma unroll
  for (int d = 1; d < 64; d <<= 1) nll += __shfl_xor(nll, d);
  __shared__ float sm[8];
  if ((tid & 63) == 0) sm[tid >> 6] = nll;
  __syncthreads();
  if (tid == 0) {
    float t = 0.f;
    for (int k = 0; k < 8; ++k) t += sm[k];
    out[0] = t * (1.0f / 512.0f);
  }
}

extern "C" void kernel_launch(void* const* d_in, const int* in_sizes, int n_in,
                              void* d_out, int out_size, void* d_ws, size_t ws_size,
                              hipStream_t stream)
{
  const float* E      = (const float*)d_in[0];
  const int*   labels = (const int*)d_in[1];
  const float* W      = (const float*)d_in[2];
  float* out = (float*)d_out;

  char* ws = (char*)d_ws;
  unsigned char* En8 = (unsigned char*)ws;              // 512*512 = 262144 B
  float* psum = (float*)(ws + 262144);                  // 256*128*4 = 131072 B
  float* pp2  = (float*)(ws + 262144 + 131072);         // 32*128*4 = 16384 B
  float* lcos = (float*)(ws + 262144 + 131072 + 16384); // 2048 B
  float* lphi = lcos + BATCH;                           // 2048 B

  knorm_e<<<BATCH, 64, 0, stream>>>(E, En8);
  klabel <<<64, 512, 0, stream>>>(E, W, labels, lcos, lphi);
  kmain  <<<256, 512, 0, stream>>>(En8, W, psum);
  kred1  <<<32, 128, 0, stream>>>(psum, pp2);
  kfinal <<<1, 512, 0, stream>>>(pp2, lcos, lphi, out);
}

// Round 8
// 107.613 us; speedup vs baseline: 2.5937x; 2.5937x over previous
//
#include <hip/hip_runtime.h>
#include <hip/hip_bf16.h>
#include <math.h>

#define BATCH 512
#define EMBED 512
#define NCLS  100000
#define NCG   128          // class column-groups
#define NBLK  512          // 4 panels x 128 cgs

typedef __attribute__((ext_vector_type(4)))  float f32x4;
typedef __attribute__((ext_vector_type(16))) float f32x16;
typedef __attribute__((ext_vector_type(2)))  long  i64x2;

constexpr float kCOS_M = 0.8775825618903728f;   // cos(0.5)
constexpr float kSIN_M = 0.4794255386042030f;   // sin(0.5)
constexpr float kTHR   = -0.8775825618903728f;  // cos(pi-0.5)
constexpr float kMM    = 0.2397127693021015f;   // sin(pi-0.5)*0.5

#define BARRIER() asm volatile("s_waitcnt lgkmcnt(0)\n\ts_barrier" ::: "memory")

__device__ __forceinline__ unsigned cvt4(float a, float b, float c, float d) {
  int v = __builtin_amdgcn_cvt_pk_fp8_f32(a, b, 0, false);
  v = __builtin_amdgcn_cvt_pk_fp8_f32(c, d, v, true);
  return (unsigned)v;
}

// ---------------- K1: normalize embeddings -> fp8 x16, PLAIN hi-split ----------
// Element k of row r -> byte (hi*16+t)*16 + half*8 + k[2:0], hi=k[3], t=k>>5,
// half=k[4]. Slot (hi,t) 16B = A-operand pair {octet(kb=2t,hi), octet(kb=2t+1,hi)}.
__global__ void knorm_e(const float* __restrict__ E, unsigned char* __restrict__ En8) {
  int r = blockIdx.x;
  int l = threadIdx.x;                       // lane owns elems 8l..8l+7
  const f32x4* src = (const f32x4*)(E + r * EMBED);
  f32x4 a = src[2 * l], b = src[2 * l + 1];
  float ss = a.x*a.x + a.y*a.y + a.z*a.z + a.w*a.w
           + b.x*b.x + b.y*b.y + b.z*b.z + b.w*b.w;
#pragma unroll
  for (int d = 1; d < 64; d <<= 1) ss += __shfl_xor(ss, d);
  float s = 16.0f / fmaxf(sqrtf(ss), 1e-12f);
  uint2 pk;
  pk.x = cvt4(a.x * s, a.y * s, a.z * s, a.w * s);
  pk.y = cvt4(b.x * s, b.y * s, b.z * s, b.w * s);
  int slotL = (l & 1) * 16 + (l >> 2);
  int half  = (l >> 1) & 1;
  *(uint2*)(En8 + r * 512 + ((slotL << 4) | (half << 3))) = pk;
}

// ---------------- K2: label-column cosine + margin in f32 ----------------
__global__ void klabel(const float* __restrict__ E, const float* __restrict__ W,
                       const int* __restrict__ labels,
                       float* __restrict__ lcos, float* __restrict__ lphi)
{
  int r = blockIdx.x * 8 + (threadIdx.x >> 6);
  int l = threadIdx.x & 63;
  int lbl = labels[r];
  const float* ep = E + (size_t)r * EMBED + l * 8;
  const float* wp = W + (size_t)lbl * EMBED + l * 8;
  f32x4 e0 = *(const f32x4*)ep, e1 = *(const f32x4*)(ep + 4);
  f32x4 w0 = *(const f32x4*)wp, w1 = *(const f32x4*)(wp + 4);
  float dot = e0.x*w0.x + e0.y*w0.y + e0.z*w0.z + e0.w*w0.w
            + e1.x*w1.x + e1.y*w1.y + e1.z*w1.z + e1.w*w1.w;
  float se = e0.x*e0.x + e0.y*e0.y + e0.z*e0.z + e0.w*e0.w
           + e1.x*e1.x + e1.y*e1.y + e1.z*e1.z + e1.w*e1.w;
  float sw = w0.x*w0.x + w0.y*w0.y + w0.z*w0.z + w0.w*w0.w
           + w1.x*w1.x + w1.y*w1.y + w1.z*w1.z + w1.w*w1.w;
#pragma unroll
  for (int d = 1; d < 64; d <<= 1) {
    dot += __shfl_xor(dot, d); se += __shfl_xor(se, d); sw += __shfl_xor(sw, d);
  }
  float cosv = dot / (fmaxf(sqrtf(se), 1e-12f) * fmaxf(sqrtf(sw), 1e-12f));
  float cc = fminf(fmaxf(cosv, -1.f), 1.f);
  float sine = sqrtf(fmaxf(1.f - cc * cc, 0.f));
  float phi = (cosv > kTHR) ? (cosv * kCOS_M - sine * kSIN_M) : (cosv - kMM);
  if (l == 0) { lcos[r] = 64.f * cosv; lphi[r] = 64.f * phi; }
}

// ---------------- K3: fused fp8 GEMM, A-fragments in REGISTERS -------------
// R6 structure (1 barrier/phase, B reg->cvt->LDS dbuf 2 phases deep), but A
// lives in 64 VGPRs/lane loaded once from global: no Asm, LDS/phase = B only.
// 512 blocks (2/CU) = 4 panels x 128 cgs, XCD-paired.
__global__ __launch_bounds__(512, 4) void kmain(
    const unsigned char* __restrict__ En8, const float* __restrict__ W,
    float* __restrict__ psum)
{
  __shared__ unsigned char Bsm[2][4096];     // 2 x 4 KB
  __shared__ float rowsum[64];
  __shared__ float smemS[2][128];

  int bid = blockIdx.x;
  int xcd = bid & 7;
  int panel = (bid >> 3) & 3;
  int grp = bid >> 5;                        // 0..15
  int cg = xcd | (grp << 3);                 // 0..127

  int tid = threadIdx.x;
  int w = tid >> 6, l = tid & 63;
  int wr = w >> 1, wc = w & 1;               // 4 row-waves x 2 col-waves
  int cl = l & 31, hi = l >> 5;
  int bcls = tid >> 3, bseg = tid & 7;       // B staging ownership

  int nt = (cg < 27) ? 13 : 12;              // 1563 = 12*128 + 27

  // ---- A fragments: 16 x 16B per lane, loaded once from global ----
  int arow = panel * 128 + wr * 32 + cl;
  const unsigned char* abase = En8 + arow * 512 + hi * 256;
  i64x2 af[16];
#pragma unroll
  for (int t = 0; t < 16; ++t) af[t] = *(const i64x2*)(abase + t * 16);

  // ---- B staging (R6 verbatim) ----
  float ssq = 0.f;
  const int boff = ((bseg & 1) * 2 + (bseg >> 2)) * 1024 + bcls * 16 + ((bseg >> 1) & 1) * 8;

  f32x4 Ra0, Ra1, Rb0, Rb1;
  auto loadB = [&](int T, int kt, f32x4& v0, f32x4& v1) {
    int cls = (cg + (T << 7)) * 64 + bcls;
    if (cls >= NCLS) cls = NCLS - 1;
    const float* p = W + (size_t)cls * EMBED + kt * 64 + bseg * 8;
    v0 = *(const f32x4*)p;
    v1 = *(const f32x4*)(p + 4);
  };
  auto writeB = [&](int buf, f32x4 v0, f32x4 v1) {
    float x0 = v0.x*128.f, x1 = v0.y*128.f, x2 = v0.z*128.f, x3 = v0.w*128.f;
    float x4 = v1.x*128.f, x5 = v1.y*128.f, x6 = v1.z*128.f, x7 = v1.w*128.f;
    ssq += x0*x0 + x1*x1 + x2*x2 + x3*x3 + x4*x4 + x5*x5 + x6*x6 + x7*x7;
    uint2 pk;
    pk.x = cvt4(x0, x1, x2, x3);
    pk.y = cvt4(x4, x5, x6, x7);
    *(uint2*)(&Bsm[buf][boff]) = pk;
  };

  f32x16 acc, S;
#pragma unroll
  for (int e = 0; e < 16; ++e) { acc[e] = 0.f; S[e] = 0.f; }

  const unsigned char* Bcol0 = &Bsm[0][(hi * 2) * 1024 + (wc * 32 + cl) * 16];
  const unsigned char* Bcol1 = &Bsm[1][(hi * 2) * 1024 + (wc * 32 + cl) * 16];

  // ---- prologue: stage phases 0,1; regs hold phases 2,3 ----
  loadB(0, 0, Ra0, Ra1);
  loadB(0, 1, Rb0, Rb1);
  writeB(0, Ra0, Ra1);
  writeB(1, Rb0, Rb1);
  loadB(0, 2, Ra0, Ra1);
  loadB(0, 3, Rb0, Rb1);
  __syncthreads();

#define PHASE(q, RS0, RS1) {                                                          \
    const unsigned char* bb = ((q) & 1) ? Bcol1 : Bcol0;                              \
    i64x2 b0 = *(const i64x2*)(bb);                                                   \
    i64x2 b1 = *(const i64x2*)(bb + 1024);                                            \
    acc = __builtin_amdgcn_mfma_f32_32x32x16_fp8_fp8(af[2*(q)][0],   b0[0], acc,0,0,0);\
    acc = __builtin_amdgcn_mfma_f32_32x32x16_fp8_fp8(af[2*(q)][1],   b0[1], acc,0,0,0);\
    acc = __builtin_amdgcn_mfma_f32_32x32x16_fp8_fp8(af[2*(q)+1][0], b1[0], acc,0,0,0);\
    acc = __builtin_amdgcn_mfma_f32_32x32x16_fp8_fp8(af[2*(q)+1][1], b1[1], acc,0,0,0);\
    if ((q) == 7) {                                                                    \
      float rs = fmaxf(rowsum[wc * 32 + cl], 1e-30f);                                  \
      float rn = 4.0f / sqrtf(rs);                                                     \
      int colg = (cg + (T << 7)) * 64 + wc * 32 + cl;                                  \
      float vm = (colg < NCLS) ? 1.0f : 0.0f;                                          \
      _Pragma("unroll")                                                                \
      for (int e = 0; e < 16; ++e) {                                                   \
        S[e] = fmaf(__expf(fmaf(acc[e], rn, -64.0f)), vm, S[e]);                       \
        acc[e] = 0.f;                                                                  \
      }                                                                                \
    }                                                                                  \
    BARRIER();                                                                         \
    if (!lastT || (q) < 6) writeB((q) & 1, RS0, RS1);                                  \
    if (!lastT || (q) < 4) loadB(T + (((q) + 4) >> 3), ((q) + 4) & 7, RS0, RS1);       \
    if ((q) == 5) {                                                                    \
      float sq = ssq;                                                                  \
      sq += __shfl_xor(sq, 1); sq += __shfl_xor(sq, 2); sq += __shfl_xor(sq, 4);       \
      if (bseg == 0) rowsum[bcls] = sq;                                                \
      ssq = 0.f;                                                                       \
    }                                                                                  \
  }

  for (int T = 0; T < nt; ++T) {
    bool lastT = (T == nt - 1);
    PHASE(0, Ra0, Ra1)
    PHASE(1, Rb0, Rb1)
    PHASE(2, Ra0, Ra1)
    PHASE(3, Rb0, Rb1)
    PHASE(4, Ra0, Ra1)
    PHASE(5, Rb0, Rb1)
    PHASE(6, Ra0, Ra1)
    PHASE(7, Rb0, Rb1)
  }
#undef PHASE

  // ---- fold S across the 32 class-lanes; combine the 2 col-waves ----
#pragma unroll
  for (int e = 0; e < 16; ++e) {
    float v = S[e];
    v += __shfl_xor(v, 1); v += __shfl_xor(v, 2); v += __shfl_xor(v, 4);
    v += __shfl_xor(v, 8); v += __shfl_xor(v, 16);
    S[e] = v;
  }
  __syncthreads();
  if (cl == 0) {
#pragma unroll
    for (int e = 0; e < 16; ++e) {
      int row = wr * 32 + (e & 3) + 8 * (e >> 2) + 4 * hi;
      smemS[wc][row] = S[e];
    }
  }
  __syncthreads();
  if (tid < 128) psum[bid * 128 + tid] = smemS[0][tid] + smemS[1][tid];
}

// ---------------- K4: reduce over the 8 XCD siblings of each (panel,grp) ----
__global__ void kred1(const float* __restrict__ psum, float* __restrict__ pp2) {
  int g = blockIdx.x;            // 0..63: panel = g>>4, grp = g&15
  int r = threadIdx.x;           // 128
  int panel = g >> 4, grp = g & 15;
  float s = 0.f;
#pragma unroll
  for (int x = 0; x < 8; ++x) {
    int bid = x | (panel << 3) | (grp << 5);
    s += psum[bid * 128 + r];
  }
  pp2[g * 128 + r] = s;
}

// ---------------- K5: final combine + label adjust + NLL mean ----------------
__global__ void kfinal(const float* __restrict__ pp2, const float* __restrict__ lcos,
                       const float* __restrict__ lphi, float* __restrict__ out)
{
  int tid = threadIdx.x;         // 512 = one thread per batch row
  int panel = tid >> 7, rl = tid & 127;
  float S = 0.f;
#pragma unroll
  for (int grp = 0; grp < 16; ++grp)
    S += pp2[((panel << 4) | grp) * 128 + rl];
  float lc = lcos[tid], lp = lphi[tid];
  S = S - __expf(lc - 64.f) + __expf(lp - 64.f);
  float nll = 64.f + __logf(S) - lp;
#pragma unroll
  for (int d = 1; d < 64; d <<= 1) nll += __shfl_xor(nll, d);
  __shared__ float sm[8];
  if ((tid & 63) == 0) sm[tid >> 6] = nll;
  __syncthreads();
  if (tid == 0) {
    float t = 0.f;
    for (int k = 0; k < 8; ++k) t += sm[k];
    out[0] = t * (1.0f / 512.0f);
  }
}

extern "C" void kernel_launch(void* const* d_in, const int* in_sizes, int n_in,
                              void* d_out, int out_size, void* d_ws, size_t ws_size,
                              hipStream_t stream)
{
  const float* E      = (const float*)d_in[0];
  const int*   labels = (const int*)d_in[1];
  const float* W      = (const float*)d_in[2];
  float* out = (float*)d_out;

  char* ws = (char*)d_ws;
  unsigned char* En8 = (unsigned char*)ws;              // 512*512 = 262144 B
  float* psum = (float*)(ws + 262144);                  // 512*128*4 = 262144 B
  float* pp2  = (float*)(ws + 524288);                  // 64*128*4 = 32768 B
  float* lcos = (float*)(ws + 557056);                  // 2048 B
  float* lphi = lcos + BATCH;                           // 2048 B

  knorm_e<<<BATCH, 64, 0, stream>>>(E, En8);
  klabel <<<64, 512, 0, stream>>>(E, W, labels, lcos, lphi);
  kmain  <<<NBLK, 512, 0, stream>>>(En8, W, psum);
  kred1  <<<64, 128, 0, stream>>>(psum, pp2);
  kfinal <<<1, 512, 0, stream>>>(pp2, lcos, lphi, out);
}

// Round 10
// 86.632 us; speedup vs baseline: 3.2219x; 1.2422x over previous
//
#include <hip/hip_runtime.h>
#include <hip/hip_bf16.h>
#include <math.h>

#define BATCH 512
#define EMBED 512
#define NCLS  100000
#define NCG   128          // class column-groups (64 classes per tile)
#define NBLK  256          // 2 panels x 128 cgs

typedef __attribute__((ext_vector_type(4)))  float f32x4;
typedef __attribute__((ext_vector_type(16))) float f32x16;
typedef __attribute__((ext_vector_type(2)))  long  i64x2;

constexpr float kCOS_M = 0.8775825618903728f;   // cos(0.5)
constexpr float kSIN_M = 0.4794255386042030f;   // sin(0.5)
constexpr float kTHR   = -0.8775825618903728f;  // cos(pi-0.5)
constexpr float kMM    = 0.2397127693021015f;   // sin(pi-0.5)*0.5

#define BARRIER() asm volatile("s_waitcnt lgkmcnt(0)\n\ts_barrier" ::: "memory")

__device__ __forceinline__ unsigned cvt4(float a, float b, float c, float d) {
  int v = __builtin_amdgcn_cvt_pk_fp8_f32(a, b, 0, false);
  v = __builtin_amdgcn_cvt_pk_fp8_f32(c, d, v, true);
  return (unsigned)v;
}

// ---------------- K1: normalize embeddings -> fp8 x16, hi-split + XOR-swizzled ----
// Element k of row r: slotL = k[3]<<4 | k[8:5], half = k[4];
// physical 16B slot = slotL ^ (r&31); byte = half*8 + k[2:0].
__global__ void knorm_e(const float* __restrict__ E, unsigned char* __restrict__ En8) {
  int r = blockIdx.x;
  int l = threadIdx.x;                       // lane owns elems 8l..8l+7
  const f32x4* src = (const f32x4*)(E + r * EMBED);
  f32x4 a = src[2 * l], b = src[2 * l + 1];
  float ss = a.x*a.x + a.y*a.y + a.z*a.z + a.w*a.w
           + b.x*b.x + b.y*b.y + b.z*b.z + b.w*b.w;
#pragma unroll
  for (int d = 1; d < 64; d <<= 1) ss += __shfl_xor(ss, d);
  float s = 16.0f / fmaxf(sqrtf(ss), 1e-12f);
  uint2 pk;
  pk.x = cvt4(a.x * s, a.y * s, a.z * s, a.w * s);
  pk.y = cvt4(b.x * s, b.y * s, b.z * s, b.w * s);
  int slotL = (l & 1) * 16 + (l >> 2);
  int half  = (l >> 1) & 1;
  *(uint2*)(En8 + r * 512 + (((slotL ^ (r & 31)) << 4) | (half << 3))) = pk;
}

// ---------------- K2: label-column cosine + margin in f32 ----------------
__global__ void klabel(const float* __restrict__ E, const float* __restrict__ W,
                       const int* __restrict__ labels,
                       float* __restrict__ lcos, float* __restrict__ lphi)
{
  int r = blockIdx.x * 8 + (threadIdx.x >> 6);
  int l = threadIdx.x & 63;
  int lbl = labels[r];
  const float* ep = E + (size_t)r * EMBED + l * 8;
  const float* wp = W + (size_t)lbl * EMBED + l * 8;
  f32x4 e0 = *(const f32x4*)ep, e1 = *(const f32x4*)(ep + 4);
  f32x4 w0 = *(const f32x4*)wp, w1 = *(const f32x4*)(wp + 4);
  float dot = e0.x*w0.x + e0.y*w0.y + e0.z*w0.z + e0.w*w0.w
            + e1.x*w1.x + e1.y*w1.y + e1.z*w1.z + e1.w*w1.w;
  float se = e0.x*e0.x + e0.y*e0.y + e0.z*e0.z + e0.w*e0.w
           + e1.x*e1.x + e1.y*e1.y + e1.z*e1.z + e1.w*e1.w;
  float sw = w0.x*w0.x + w0.y*w0.y + w0.z*w0.z + w0.w*w0.w
           + w1.x*w1.x + w1.y*w1.y + w1.z*w1.z + w1.w*w1.w;
#pragma unroll
  for (int d = 1; d < 64; d <<= 1) {
    dot += __shfl_xor(dot, d); se += __shfl_xor(se, d); sw += __shfl_xor(sw, d);
  }
  float cosv = dot / (fmaxf(sqrtf(se), 1e-12f) * fmaxf(sqrtf(sw), 1e-12f));
  float cc = fminf(fmaxf(cosv, -1.f), 1.f);
  float sine = sqrtf(fmaxf(1.f - cc * cc, 0.f));
  float phi = (cosv > kTHR) ? (cosv * kCOS_M - sine * kSIN_M) : (cosv - kMM);
  if (l == 0) { lcos[r] = 64.f * cosv; lphi[r] = 64.f * phi; }
}

// ---------------- K3: fused fp8 GEMM + fixed-max expsum (BM=256) -----------
// 256 blocks (1/CU) = 2 panels x 128 cgs. A panel (256 x 512 fp8 = 128KB)
// LDS-resident; B (16KB f32/phase) reg-staged (16B/thread) -> cvt fp8 ->
// 2-buffer LDS with R6's PROVEN schedule: one barrier per phase, writes of
// phase p+2 directly after the barrier ending phase p's reads, loads 4 ahead.
__global__ __launch_bounds__(1024, 4) void kmain(
    const unsigned char* __restrict__ En8, const float* __restrict__ W,
    float* __restrict__ psum)
{
  __shared__ __align__(16) unsigned char Asm[256 * 512];   // 128 KB
  __shared__ __align__(16) unsigned char Bsm[2][4096];     // 8 KB
  __shared__ float rowsum[64];
  __shared__ float smemS[2][256];

  int bid = blockIdx.x;
  int xcd = bid & 7;
  int panel = (bid >> 3) & 1;
  int grp = bid >> 4;                        // 0..15
  int cg = xcd | (grp << 3);                 // 0..127

  int tid = threadIdx.x;
  int w = tid >> 6, l = tid & 63;
  int wr = w >> 1, wc = w & 1;               // 8 row-waves x 2 col-waves
  int cl = l & 31, hi = l >> 5;
  int bcls = tid >> 4, bs = tid & 15;        // B staging: class, 4-float k-seg

  int nt = (cg < 27) ? 13 : 12;              // 1563 = 12*128 + 27
  int nph = nt * 8;

  // ---- stage A panel once: pure linear glds (source pre-swizzled) ----
#pragma unroll
  for (int i = 0; i < 8; ++i) {
    int base = i * 16384 + w * 1024;
    __builtin_amdgcn_global_load_lds(
        (const __attribute__((address_space(1))) void*)(En8 + panel * 131072 + base + l * 16),
        (__attribute__((address_space(3))) void*)(&Asm[base]), 16, 0, 0);
  }

  float ssq = 0.f;
  // write target: region = k3*2 + k5, half = k4, byte4 = k2   (k[5:2] = bs)
  const int boff = (((bs >> 1) & 1) * 2 + (bs >> 3)) * 1024 + bcls * 16
                 + ((bs >> 2) & 1) * 8 + (bs & 1) * 4;

  f32x4 Ra, Rb;
  auto loadB = [&](int q, f32x4& v) {
    int cls = (cg + ((q >> 3) << 7)) * 64 + bcls;
    if (cls >= NCLS) cls = NCLS - 1;
    v = *(const f32x4*)(W + (size_t)cls * EMBED + (q & 7) * 64 + bs * 4);
  };
  auto writeB = [&](int buf, f32x4 v) {
    float x0 = v.x*128.f, x1 = v.y*128.f, x2 = v.z*128.f, x3 = v.w*128.f;
    ssq += x0*x0 + x1*x1 + x2*x2 + x3*x3;
    *(unsigned*)(&Bsm[buf][boff]) = cvt4(x0, x1, x2, x3);
  };

  f32x16 acc, S;
#pragma unroll
  for (int e = 0; e < 16; ++e) { acc[e] = 0.f; S[e] = 0.f; }

  const unsigned char* Abase = &Asm[(wr * 32 + cl) * 512];
  const unsigned char* Bcol0 = &Bsm[0][(hi * 2) * 1024 + (wc * 32 + cl) * 16];
  const unsigned char* Bcol1 = &Bsm[1][(hi * 2) * 1024 + (wc * 32 + cl) * 16];

  auto compute = [&](const unsigned char* bb, int pt) {
    int t0 = pt * 2;
    i64x2 a0 = *(const i64x2*)(Abase + ((((hi << 4) | t0)       ^ cl) << 4));
    i64x2 a1 = *(const i64x2*)(Abase + ((((hi << 4) | (t0 + 1)) ^ cl) << 4));
    i64x2 b0 = *(const i64x2*)(bb);
    i64x2 b1 = *(const i64x2*)(bb + 1024);
    acc = __builtin_amdgcn_mfma_f32_32x32x16_fp8_fp8(a0[0], b0[0], acc, 0, 0, 0);
    acc = __builtin_amdgcn_mfma_f32_32x32x16_fp8_fp8(a0[1], b0[1], acc, 0, 0, 0);
    acc = __builtin_amdgcn_mfma_f32_32x32x16_fp8_fp8(a1[0], b1[0], acc, 0, 0, 0);
    acc = __builtin_amdgcn_mfma_f32_32x32x16_fp8_fp8(a1[1], b1[1], acc, 0, 0, 0);
  };

  auto ssqred = [&]() {
    float sq = ssq;
    sq += __shfl_xor(sq, 1); sq += __shfl_xor(sq, 2);
    sq += __shfl_xor(sq, 4); sq += __shfl_xor(sq, 8);
    if (bs == 0) rowsum[bcls] = sq;
    ssq = 0.f;
  };

  auto epilogue = [&](int T) {
    float rs = fmaxf(rowsum[wc * 32 + cl], 1e-30f);
    float rn = 4.0f / sqrtf(rs);
    int colg = (cg + (T << 7)) * 64 + wc * 32 + cl;
    float vm = (colg < NCLS) ? 1.0f : 0.0f;
#pragma unroll
    for (int e = 0; e < 16; ++e) {
      S[e] = fmaf(__expf(fmaf(acc[e], rn, -64.0f)), vm, S[e]);
      acc[e] = 0.f;
    }
  };

  // ---- prologue: stage phases 0,1; regs hold phases 2,3 ----
  loadB(0, Ra); loadB(1, Rb);
  writeB(0, Ra); writeB(1, Rb);
  loadB(2, Ra); loadB(3, Rb);
  asm volatile("s_waitcnt vmcnt(0)" ::: "memory");   // A + Bsm[0/1] staged
  BARRIER();

  for (int p = 0; p < nph; p += 2) {
    // -------- even phase --------
    compute(Bcol0, p & 7);
    BARRIER();                                  // readers done with Bsm[0]
    if (p + 2 < nph) writeB(0, Ra);             // stage phase p+2
    if (p + 4 < nph) loadB(p + 4, Ra);
    // -------- odd phase --------
    int po = p + 1;
    compute(Bcol1, po & 7);                     // Bsm[1] write(prev) fenced by BARRIER above
    if ((po & 7) == 7) epilogue(po >> 3);       // rowsum from ssqred, fenced
    BARRIER();                                  // readers done with Bsm[1]
    if (po + 2 < nph) writeB(1, Rb);            // stage phase po+2
    if (po + 4 < nph) loadB(po + 4, Rb);
    if (((po + 2) & 7) == 7) ssqred();          // tile's 8 chunks all staged
  }

  // ---- fold S across the 32 class-lanes; combine the 2 col-waves ----
#pragma unroll
  for (int e = 0; e < 16; ++e) {
    float v = S[e];
    v += __shfl_xor(v, 1); v += __shfl_xor(v, 2); v += __shfl_xor(v, 4);
    v += __shfl_xor(v, 8); v += __shfl_xor(v, 16);
    S[e] = v;
  }
  __syncthreads();
  if (cl == 0) {
#pragma unroll
    for (int e = 0; e < 16; ++e) {
      int row = wr * 32 + (e & 3) + 8 * (e >> 2) + 4 * hi;
      smemS[wc][row] = S[e];
    }
  }
  __syncthreads();
  if (tid < 256) psum[bid * 256 + tid] = smemS[0][tid] + smemS[1][tid];
}

// ---------------- K4: reduce over the 8 XCD siblings of each (panel,grp) ----
__global__ void kred1(const float* __restrict__ psum, float* __restrict__ pp2) {
  int g = blockIdx.x;            // 0..31: panel = g>>4, grp = g&15
  int r = threadIdx.x;           // 256
  int panel = g >> 4, grp = g & 15;
  float s = 0.f;
#pragma unroll
  for (int x = 0; x < 8; ++x) {
    int bid = x | (panel << 3) | (grp << 4);
    s += psum[bid * 256 + r];
  }
  pp2[g * 256 + r] = s;
}

// ---------------- K5: final combine + label adjust + NLL mean ----------------
__global__ void kfinal(const float* __restrict__ pp2, const float* __restrict__ lcos,
                       const float* __restrict__ lphi, float* __restrict__ out)
{
  int tid = threadIdx.x;         // 512 = one thread per batch row
  int panel = tid >> 8, rl = tid & 255;
  float S = 0.f;
#pragma unroll
  for (int grp = 0; grp < 16; ++grp)
    S += pp2[((panel << 4) | grp) * 256 + rl];
  float lc = lcos[tid], lp = lphi[tid];
  S = S - __expf(lc - 64.f) + __expf(lp - 64.f);
  float nll = 64.f + __logf(S) - lp;
#pragma unroll
  for (int d = 1; d < 64; d <<= 1) nll += __shfl_xor(nll, d);
  __shared__ float sm[8];
  if ((tid & 63) == 0) sm[tid >> 6] = nll;
  __syncthreads();
  if (tid == 0) {
    float t = 0.f;
    for (int k = 0; k < 8; ++k) t += sm[k];
    out[0] = t * (1.0f / 512.0f);
  }
}

extern "C" void kernel_launch(void* const* d_in, const int* in_sizes, int n_in,
                              void* d_out, int out_size, void* d_ws, size_t ws_size,
                              hipStream_t stream)
{
  const float* E      = (const float*)d_in[0];
  const int*   labels = (const int*)d_in[1];
  const float* W      = (const float*)d_in[2];
  float* out = (float*)d_out;

  char* ws = (char*)d_ws;
  unsigned char* En8 = (unsigned char*)ws;              // 512*512 = 262144 B
  float* psum = (float*)(ws + 262144);                  // 256*256*4 = 262144 B
  float* pp2  = (float*)(ws + 524288);                  // 32*256*4 = 32768 B
  float* lcos = (float*)(ws + 557056);                  // 2048 B
  float* lphi = lcos + BATCH;                           // 2048 B

  knorm_e<<<BATCH, 64, 0, stream>>>(E, En8);
  klabel <<<64, 512, 0, stream>>>(E, W, labels, lcos, lphi);
  kmain  <<<NBLK, 1024, 0, stream>>>(En8, W, psum);
  kred1  <<<32, 256, 0, stream>>>(psum, pp2);
  kfinal <<<1, 512, 0, stream>>>(pp2, lcos, lphi, out);
}

// Round 11
// 80.829 us; speedup vs baseline: 3.4532x; 1.0718x over previous
//
#include <hip/hip_runtime.h>
#include <hip/hip_bf16.h>
#include <math.h>

#define BATCH 512
#define EMBED 512
#define NCLS  100000
#define NT128 782          // ceil(100000/128) class tiles of 128
#define NCG   128          // column groups
#define NBLK  256          // 2 panels x 128 cgs

typedef __attribute__((ext_vector_type(4)))  float f32x4;
typedef __attribute__((ext_vector_type(16))) float f32x16;
typedef __attribute__((ext_vector_type(2)))  long  i64x2;

constexpr float kCOS_M = 0.8775825618903728f;   // cos(0.5)
constexpr float kSIN_M = 0.4794255386042030f;   // sin(0.5)
constexpr float kTHR   = -0.8775825618903728f;  // cos(pi-0.5)
constexpr float kMM    = 0.2397127693021015f;   // sin(pi-0.5)*0.5

#define BARRIER() asm volatile("s_waitcnt lgkmcnt(0)\n\ts_barrier" ::: "memory")

__device__ __forceinline__ unsigned cvt4(float a, float b, float c, float d) {
  int v = __builtin_amdgcn_cvt_pk_fp8_f32(a, b, 0, false);
  v = __builtin_amdgcn_cvt_pk_fp8_f32(c, d, v, true);
  return (unsigned)v;
}

// ---------------- K1: normalize embeddings -> fp8 x16, hi-split + XOR-swizzled ----
// (R10 verbatim) Element k of row r: slotL = k[3]<<4 | k[8:5], half = k[4];
// physical 16B slot = slotL ^ (r&31); byte = half*8 + k[2:0].
__global__ void knorm_e(const float* __restrict__ E, unsigned char* __restrict__ En8) {
  int r = blockIdx.x;
  int l = threadIdx.x;                       // lane owns elems 8l..8l+7
  const f32x4* src = (const f32x4*)(E + r * EMBED);
  f32x4 a = src[2 * l], b = src[2 * l + 1];
  float ss = a.x*a.x + a.y*a.y + a.z*a.z + a.w*a.w
           + b.x*b.x + b.y*b.y + b.z*b.z + b.w*b.w;
#pragma unroll
  for (int d = 1; d < 64; d <<= 1) ss += __shfl_xor(ss, d);
  float s = 16.0f / fmaxf(sqrtf(ss), 1e-12f);
  uint2 pk;
  pk.x = cvt4(a.x * s, a.y * s, a.z * s, a.w * s);
  pk.y = cvt4(b.x * s, b.y * s, b.z * s, b.w * s);
  int slotL = (l & 1) * 16 + (l >> 2);
  int half  = (l >> 1) & 1;
  *(uint2*)(En8 + r * 512 + (((slotL ^ (r & 31)) << 4) | (half << 3))) = pk;
}

// ---------------- K2: label-column cosine + margin in f32 ----------------
__global__ void klabel(const float* __restrict__ E, const float* __restrict__ W,
                       const int* __restrict__ labels,
                       float* __restrict__ lcos, float* __restrict__ lphi)
{
  int r = blockIdx.x * 8 + (threadIdx.x >> 6);
  int l = threadIdx.x & 63;
  int lbl = labels[r];
  const float* ep = E + (size_t)r * EMBED + l * 8;
  const float* wp = W + (size_t)lbl * EMBED + l * 8;
  f32x4 e0 = *(const f32x4*)ep, e1 = *(const f32x4*)(ep + 4);
  f32x4 w0 = *(const f32x4*)wp, w1 = *(const f32x4*)(wp + 4);
  float dot = e0.x*w0.x + e0.y*w0.y + e0.z*w0.z + e0.w*w0.w
            + e1.x*w1.x + e1.y*w1.y + e1.z*w1.z + e1.w*w1.w;
  float se = e0.x*e0.x + e0.y*e0.y + e0.z*e0.z + e0.w*e0.w
           + e1.x*e1.x + e1.y*e1.y + e1.z*e1.z + e1.w*e1.w;
  float sw = w0.x*w0.x + w0.y*w0.y + w0.z*w0.z + w0.w*w0.w
           + w1.x*w1.x + w1.y*w1.y + w1.z*w1.z + w1.w*w1.w;
#pragma unroll
  for (int d = 1; d < 64; d <<= 1) {
    dot += __shfl_xor(dot, d); se += __shfl_xor(se, d); sw += __shfl_xor(sw, d);
  }
  float cosv = dot / (fmaxf(sqrtf(se), 1e-12f) * fmaxf(sqrtf(sw), 1e-12f));
  float cc = fminf(fmaxf(cosv, -1.f), 1.f);
  float sine = sqrtf(fmaxf(1.f - cc * cc, 0.f));
  float phi = (cosv > kTHR) ? (cosv * kCOS_M - sine * kSIN_M) : (cosv - kMM);
  if (l == 0) { lcos[r] = 64.f * cosv; lphi[r] = 64.f * phi; }
}

// ---------------- K3: fused fp8 GEMM + fixed-max expsum -------------------
// BM=256, B-tile=128 classes/phase. 256 blocks (1/CU) = 2 panels x 128 cgs.
// A panel (256x512 fp8 = 128KB) LDS-resident. Waves: 8 row x 2 col, each
// 32 rows x 64 classes (acc0/acc1). R10's proven schedule: one barrier per
// phase, write p+2 after the barrier ending p's reads, loads 4 phases ahead.
__global__ __launch_bounds__(1024, 4) void kmain(
    const unsigned char* __restrict__ En8, const float* __restrict__ W,
    float* __restrict__ psum)
{
  __shared__ __align__(16) unsigned char Asm[256 * 512];   // 128 KB
  __shared__ __align__(16) unsigned char Bsm[2][8192];     // 16 KB
  __shared__ float rowsum[128];
  __shared__ float smemS[2][256];

  int bid = blockIdx.x;
  int xcd = bid & 7;
  int panel = (bid >> 3) & 1;
  int grp = bid >> 4;                        // 0..15
  int cg = xcd | (grp << 3);                 // 0..127

  int tid = threadIdx.x;
  int w = tid >> 6, l = tid & 63;
  int wr = w >> 1, wc = w & 1;               // 8 row-waves x 2 col-waves
  int cl = l & 31, hi = l >> 5;
  int bcls = tid >> 3, bs3 = tid & 7;        // B staging: class(0..127), 32B k-seg

  int nt = (NT128 - cg + 127) >> 7;          // 7 (cg<14) else 6; sum = 782
  int nph = nt * 8;

  // ---- stage A panel once: pure linear glds (source pre-swizzled) ----
#pragma unroll
  for (int i = 0; i < 8; ++i) {
    int base = i * 16384 + w * 1024;
    __builtin_amdgcn_global_load_lds(
        (const __attribute__((address_space(1))) void*)(En8 + panel * 131072 + base + l * 16),
        (__attribute__((address_space(3))) void*)(&Asm[base]), 16, 0, 0);
  }

  float ssq = 0.f;
  // thread's 8 floats = old granules bs_a=2*bs3, bs_a+1 -> one 8B write at
  // boff(bs_a): region = (bs3&1)*2 + (bs3>>2), half = (bs3>>1)&1, word 0.
  const int boff = (bcls >> 6) * 4096
                 + ((bs3 & 1) * 2 + (bs3 >> 2)) * 1024
                 + (bcls & 63) * 16 + ((bs3 >> 1) & 1) * 8;

  f32x4 Ra0, Ra1, Rb0, Rb1;
  auto loadB = [&](int q, f32x4& v0, f32x4& v1) {
    int cls = (cg + ((q >> 3) << 7)) * 128 + bcls;
    if (cls >= NCLS) cls = NCLS - 1;
    const float* p = W + (size_t)cls * EMBED + (q & 7) * 64 + bs3 * 8;
    v0 = *(const f32x4*)p;
    v1 = *(const f32x4*)(p + 4);
  };
  auto writeB = [&](int buf, f32x4 v0, f32x4 v1) {
    float x0 = v0.x*128.f, x1 = v0.y*128.f, x2 = v0.z*128.f, x3 = v0.w*128.f;
    float x4 = v1.x*128.f, x5 = v1.y*128.f, x6 = v1.z*128.f, x7 = v1.w*128.f;
    ssq += x0*x0 + x1*x1 + x2*x2 + x3*x3 + x4*x4 + x5*x5 + x6*x6 + x7*x7;
    uint2 pk;
    pk.x = cvt4(x0, x1, x2, x3);
    pk.y = cvt4(x4, x5, x6, x7);
    *(uint2*)(&Bsm[buf][boff]) = pk;
  };

  f32x16 acc0, acc1, S;
#pragma unroll
  for (int e = 0; e < 16; ++e) { acc0[e] = 0.f; acc1[e] = 0.f; S[e] = 0.f; }

  const unsigned char* Abase = &Asm[(wr * 32 + cl) * 512];
  const unsigned char* Bc0 = &Bsm[0][wc * 4096 + (hi * 2) * 1024 + cl * 16];
  const unsigned char* Bc1 = &Bsm[1][wc * 4096 + (hi * 2) * 1024 + cl * 16];

  auto compute = [&](const unsigned char* bb, int pt) {
    int t0 = pt * 2;
    i64x2 a0 = *(const i64x2*)(Abase + ((((hi << 4) | t0)       ^ cl) << 4));
    i64x2 a1 = *(const i64x2*)(Abase + ((((hi << 4) | (t0 + 1)) ^ cl) << 4));
    i64x2 b0 = *(const i64x2*)(bb);
    i64x2 b1 = *(const i64x2*)(bb + 1024);
    i64x2 c0 = *(const i64x2*)(bb + 512);
    i64x2 c1 = *(const i64x2*)(bb + 1024 + 512);
    acc0 = __builtin_amdgcn_mfma_f32_32x32x16_fp8_fp8(a0[0], b0[0], acc0, 0, 0, 0);
    acc0 = __builtin_amdgcn_mfma_f32_32x32x16_fp8_fp8(a0[1], b0[1], acc0, 0, 0, 0);
    acc0 = __builtin_amdgcn_mfma_f32_32x32x16_fp8_fp8(a1[0], b1[0], acc0, 0, 0, 0);
    acc0 = __builtin_amdgcn_mfma_f32_32x32x16_fp8_fp8(a1[1], b1[1], acc0, 0, 0, 0);
    acc1 = __builtin_amdgcn_mfma_f32_32x32x16_fp8_fp8(a0[0], c0[0], acc1, 0, 0, 0);
    acc1 = __builtin_amdgcn_mfma_f32_32x32x16_fp8_fp8(a0[1], c0[1], acc1, 0, 0, 0);
    acc1 = __builtin_amdgcn_mfma_f32_32x32x16_fp8_fp8(a1[0], c1[0], acc1, 0, 0, 0);
    acc1 = __builtin_amdgcn_mfma_f32_32x32x16_fp8_fp8(a1[1], c1[1], acc1, 0, 0, 0);
  };

  auto ssqred = [&]() {
    float sq = ssq;
    sq += __shfl_xor(sq, 1); sq += __shfl_xor(sq, 2); sq += __shfl_xor(sq, 4);
    if (bs3 == 0) rowsum[bcls] = sq;
    ssq = 0.f;
  };

  auto epilogue = [&](int T) {
    int base = (cg + (T << 7)) * 128 + wc * 64;
    float rs0 = fmaxf(rowsum[wc * 64 + cl], 1e-30f);
    float rs1 = fmaxf(rowsum[wc * 64 + 32 + cl], 1e-30f);
    float rn0 = 4.0f / sqrtf(rs0);
    float rn1 = 4.0f / sqrtf(rs1);
    float vm0 = (base + cl < NCLS) ? 1.0f : 0.0f;
    float vm1 = (base + 32 + cl < NCLS) ? 1.0f : 0.0f;
#pragma unroll
    for (int e = 0; e < 16; ++e) {
      float u0 = __expf(fmaf(acc0[e], rn0, -64.0f));
      float u1 = __expf(fmaf(acc1[e], rn1, -64.0f));
      S[e] = fmaf(u0, vm0, fmaf(u1, vm1, S[e]));
      acc0[e] = 0.f; acc1[e] = 0.f;
    }
  };

  // ---- prologue: stage phases 0,1; regs hold phases 2,3 ----
  loadB(0, Ra0, Ra1); loadB(1, Rb0, Rb1);
  writeB(0, Ra0, Ra1); writeB(1, Rb0, Rb1);
  loadB(2, Ra0, Ra1); loadB(3, Rb0, Rb1);
  asm volatile("s_waitcnt vmcnt(0)" ::: "memory");   // A + Bsm[0/1] staged
  BARRIER();

  for (int p = 0; p < nph; p += 2) {
    // -------- even phase --------
    compute(Bc0, p & 7);
    BARRIER();                                  // readers done with Bsm[0]
    if (p + 2 < nph) writeB(0, Ra0, Ra1);       // stage phase p+2
    if (p + 4 < nph) loadB(p + 4, Ra0, Ra1);
    // -------- odd phase --------
    int po = p + 1;
    compute(Bc1, po & 7);
    if ((po & 7) == 7) epilogue(po >> 3);       // rowsum fenced one barrier ago
    BARRIER();                                  // readers done with Bsm[1]
    if (po + 2 < nph) writeB(1, Rb0, Rb1);      // stage phase po+2
    if (po + 4 < nph) loadB(po + 4, Rb0, Rb1);
    if (((po + 2) & 7) == 7) ssqred();          // tile's 8 chunks all staged
  }

  // ---- fold S across the 32 class-lanes; combine the 2 col-waves ----
#pragma unroll
  for (int e = 0; e < 16; ++e) {
    float v = S[e];
    v += __shfl_xor(v, 1); v += __shfl_xor(v, 2); v += __shfl_xor(v, 4);
    v += __shfl_xor(v, 8); v += __shfl_xor(v, 16);
    S[e] = v;
  }
  __syncthreads();
  if (cl == 0) {
#pragma unroll
    for (int e = 0; e < 16; ++e) {
      int row = wr * 32 + (e & 3) + 8 * (e >> 2) + 4 * hi;
      smemS[wc][row] = S[e];
    }
  }
  __syncthreads();
  if (tid < 256) psum[bid * 256 + tid] = smemS[0][tid] + smemS[1][tid];
}

// ---------------- K4: reduce over the 8 XCD siblings of each (panel,grp) ----
__global__ void kred1(const float* __restrict__ psum, float* __restrict__ pp2) {
  int g = blockIdx.x;            // 0..31: panel = g>>4, grp = g&15
  int r = threadIdx.x;           // 256
  int panel = g >> 4, grp = g & 15;
  float s = 0.f;
#pragma unroll
  for (int x = 0; x < 8; ++x) {
    int bid = x | (panel << 3) | (grp << 4);
    s += psum[bid * 256 + r];
  }
  pp2[g * 256 + r] = s;
}

// ---------------- K5: final combine + label adjust + NLL mean ----------------
__global__ void kfinal(const float* __restrict__ pp2, const float* __restrict__ lcos,
                       const float* __restrict__ lphi, float* __restrict__ out)
{
  int tid = threadIdx.x;         // 512 = one thread per batch row
  int panel = tid >> 8, rl = tid & 255;
  float S = 0.f;
#pragma unroll
  for (int grp = 0; grp < 16; ++grp)
    S += pp2[((panel << 4) | grp) * 256 + rl];
  float lc = lcos[tid], lp = lphi[tid];
  S = S - __expf(lc - 64.f) + __expf(lp - 64.f);
  float nll = 64.f + __logf(S) - lp;
#pragma unroll
  for (int d = 1; d < 64; d <<= 1) nll += __shfl_xor(nll, d);
  __shared__ float sm[8];
  if ((tid & 63) == 0) sm[tid >> 6] = nll;
  __syncthreads();
  if (tid == 0) {
    float t = 0.f;
    for (int k = 0; k < 8; ++k) t += sm[k];
    out[0] = t * (1.0f / 512.0f);
  }
}

extern "C" void kernel_launch(void* const* d_in, const int* in_sizes, int n_in,
                              void* d_out, int out_size, void* d_ws, size_t ws_size,
                              hipStream_t stream)
{
  const float* E      = (const float*)d_in[0];
  const int*   labels = (const int*)d_in[1];
  const float* W      = (const float*)d_in[2];
  float* out = (float*)d_out;

  char* ws = (char*)d_ws;
  unsigned char* En8 = (unsigned char*)ws;              // 512*512 = 262144 B
  float* psum = (float*)(ws + 262144);                  // 256*256*4 = 262144 B
  float* pp2  = (float*)(ws + 524288);                  // 32*256*4 = 32768 B
  float* lcos = (float*)(ws + 557056);                  // 2048 B
  float* lphi = lcos + BATCH;                           // 2048 B

  knorm_e<<<BATCH, 64, 0, stream>>>(E, En8);
  klabel <<<64, 512, 0, stream>>>(E, W, labels, lcos, lphi);
  kmain  <<<NBLK, 1024, 0, stream>>>(En8, W, psum);
  kred1  <<<32, 256, 0, stream>>>(psum, pp2);
  kfinal <<<1, 512, 0, stream>>>(pp2, lcos, lphi, out);
}